// Round 3
// baseline (60.748 us; speedup 1.0000x reference)
//
#include <hip/hip_runtime.h>
#include <math.h>

// QConv2d: new_rho = kron(Ux,Uy) @ rho @ kron(Ux,Uy)^T
// Ux,Uy 32x32 block-diagonal with four IDENTICAL 8x8 orthogonal blocks.
// Four independent length-8 contractions on axes (x1,y1,x2,y2).
//
// Fused kernel, block = (b,bx1,by1,bx2) = 64 rows x 256 contiguous cols:
//  - thread t owns global column bx2*256+t: 64 coalesced dword loads,
//    contracts y1,x1 in registers (1024 FMA),
//  - one LDS transpose, swizzled F(r,c)=r*256+(((c>>2)^(r&7))<<2)+(c&3):
//    scalar writes (2-way, free) / b128 reads (optimal), imm-offset addressing,
//  - thread (r=t&63, by2=t>>6) contracts y2,x2 in registers,
//  - direct float4 stores (4 waves fill complementary 16B sector pieces;
//    L2 write-combines).

__global__ void setup_uf(const float* __restrict__ phi_x,
                         const float* __restrict__ phi_y,
                         float* __restrict__ ws) {
    const int t = threadIdx.x;
    if (t < 2) {
        const float* phi = (t == 0) ? phi_x : phi_y;
        float U[8][8];
#pragma unroll
        for (int i = 0; i < 8; ++i)
#pragma unroll
            for (int j = 0; j < 8; ++j) U[i][j] = (i == j) ? 1.0f : 0.0f;
        int idx = 0;
#pragma unroll
        for (int i = 1; i < 8; ++i) {
#pragma unroll
            for (int j = i; j >= 1; --j) {
                const float c = cosf(phi[idx]);
                const float s = sinf(phi[idx]);
#pragma unroll
                for (int m = 0; m < 8; ++m) {
                    const float a = U[j - 1][m], b = U[j][m];
                    U[j - 1][m] = c * a + s * b;
                    U[j][m]     = -s * a + c * b;
                }
                ++idx;
            }
        }
        float* o = ws + t * 64;
#pragma unroll
        for (int i = 0; i < 8; ++i)
#pragma unroll
            for (int j = 0; j < 8; ++j) o[i * 8 + j] = U[i][j];
    }
}

// contract the INNER index (stride 1 within groups of 8) of a[64] with M[8][8]
#define CONTRACT_INNER(M, a)                                                   \
    _Pragma("unroll")                                                          \
    for (int _g = 0; _g < 8; ++_g) {                                           \
        float _tmp[8];                                                         \
        _Pragma("unroll")                                                      \
        for (int _i = 0; _i < 8; ++_i) {                                       \
            float _acc = 0.0f;                                                 \
            _Pragma("unroll")                                                  \
            for (int _k = 0; _k < 8; ++_k)                                     \
                _acc = fmaf((M)[_i * 8 + _k], (a)[_g * 8 + _k], _acc);         \
            _tmp[_i] = _acc;                                                   \
        }                                                                      \
        _Pragma("unroll")                                                      \
        for (int _i = 0; _i < 8; ++_i) (a)[_g * 8 + _i] = _tmp[_i];            \
    }

// contract the OUTER index (stride 8) of a[64] with M[8][8]
#define CONTRACT_OUTER(M, a)                                                   \
    _Pragma("unroll")                                                          \
    for (int _g = 0; _g < 8; ++_g) {                                           \
        float _tmp[8];                                                         \
        _Pragma("unroll")                                                      \
        for (int _i = 0; _i < 8; ++_i) {                                       \
            float _acc = 0.0f;                                                 \
            _Pragma("unroll")                                                  \
            for (int _k = 0; _k < 8; ++_k)                                     \
                _acc = fmaf((M)[_i * 8 + _k], (a)[_k * 8 + _g], _acc);         \
            _tmp[_i] = _acc;                                                   \
        }                                                                      \
        _Pragma("unroll")                                                      \
        for (int _i = 0; _i < 8; ++_i) (a)[_i * 8 + _g] = _tmp[_i];            \
    }

__global__ __launch_bounds__(256) void qconv_fused(const float* __restrict__ rho,
                                                   const float* __restrict__ ws,
                                                   float* __restrict__ out) {
    __shared__ float S[16384];  // [64 rows][256 cols] swizzled, 64 KB
    const int t   = threadIdx.x;
    const int bid = blockIdx.x;
    const int bx2 = bid & 3;
    const int by1 = (bid >> 2) & 3;
    const int bx1 = (bid >> 4) & 3;
    const int b   = bid >> 6;

    const float* __restrict__ UX = ws;       // Ufx[8][8] (wave-uniform -> s_load)
    const float* __restrict__ UY = ws + 64;  // Ufy[8][8]

    const size_t B0      = (size_t)b << 20;
    const int    rowbase = bx1 * 256 + by1 * 8;
    const int    cg      = bx2 * 256 + t;

    // ---- load 64 rows at column cg (coalesced dwords) ----
    const float* __restrict__ src = rho + B0 + (size_t)rowbase * 1024 + cg;
    float v[64];
#pragma unroll
    for (int i = 0; i < 8; ++i)
#pragma unroll
        for (int j = 0; j < 8; ++j)
            v[i * 8 + j] = src[(i * 32 + j) * 1024];

    // ---- row transform in registers ----
    CONTRACT_INNER(UY, v)
    CONTRACT_OUTER(UX, v)

    // ---- scatter to LDS (swizzled scalar writes, imm-offset r*1024B) ----
    {
        int cb8[8];
#pragma unroll
        for (int r7 = 0; r7 < 8; ++r7)
            cb8[r7] = (((t >> 2) ^ r7) << 2) | (t & 3);
#pragma unroll
        for (int r = 0; r < 64; ++r) S[r * 256 + cb8[r & 7]] = v[r];
    }
    __syncthreads();

    // ---- transposed view: thread = (row rr, col-group by2) ----
    const int rr    = t & 63;
    const int by2   = t >> 6;
    const int r7    = rr & 7;
    const int rbase = rr * 256;
    const int vb0   = rbase + ((((by2 * 2) + 0) ^ r7) << 2);
    const int vb1   = rbase + ((((by2 * 2) + 1) ^ r7) << 2);

    float p[64];
#pragma unroll
    for (int x = 0; x < 8; ++x) {
        const float4 q0 = *reinterpret_cast<const float4*>(&S[vb0 + x * 32]);
        const float4 q1 = *reinterpret_cast<const float4*>(&S[vb1 + x * 32]);
        p[x * 8 + 0] = q0.x; p[x * 8 + 1] = q0.y;
        p[x * 8 + 2] = q0.z; p[x * 8 + 3] = q0.w;
        p[x * 8 + 4] = q1.x; p[x * 8 + 5] = q1.y;
        p[x * 8 + 6] = q1.z; p[x * 8 + 7] = q1.w;
    }

    // ---- col transform in registers ----
    CONTRACT_INNER(UY, p)
    CONTRACT_OUTER(UX, p)

    // ---- direct stores: row gr, cols bx2*256 + x*32 + by2*8 + [0,8) ----
    const int gr = rowbase + ((rr >> 3) * 32) + (rr & 7);
    float* __restrict__ dst = out + B0 + (size_t)gr * 1024 + bx2 * 256 + by2 * 8;
#pragma unroll
    for (int x = 0; x < 8; ++x) {
        *reinterpret_cast<float4*>(dst + x * 32) =
            make_float4(p[x * 8 + 0], p[x * 8 + 1], p[x * 8 + 2], p[x * 8 + 3]);
        *reinterpret_cast<float4*>(dst + x * 32 + 4) =
            make_float4(p[x * 8 + 4], p[x * 8 + 5], p[x * 8 + 6], p[x * 8 + 7]);
    }
}

extern "C" void kernel_launch(void* const* d_in, const int* in_sizes, int n_in,
                              void* d_out, int out_size, void* d_ws, size_t ws_size,
                              hipStream_t stream) {
    const float* rho   = (const float*)d_in[0];
    const float* phi_x = (const float*)d_in[1];
    const float* phi_y = (const float*)d_in[2];
    float* out = (float*)d_out;
    float* ws  = (float*)d_ws;

    setup_uf<<<1, 64, 0, stream>>>(phi_x, phi_y, ws);
    qconv_fused<<<1024, 256, 0, stream>>>(rho, ws, out);
}

// Round 4
// 43.814 us; speedup vs baseline: 1.3865x; 1.3865x over previous
//
#include <hip/hip_runtime.h>
#include <math.h>

// QConv2d: new_rho = kron(Ux,Uy) @ rho @ kron(Ux,Uy)^T
// Ux,Uy 32x32 block-diagonal with four IDENTICAL 8x8 orthogonal blocks.
// Four independent length-8 contractions on axes (x1,y1,x2,y2).
//
// Fused kernel, block = (b,bx1,by1,bx2) = 64 rows x 256 contiguous cols.
// Transpose via a 32KB [32][256] LDS buffer in TWO half-passes (rows 0..31,
// then 32..63) so 4 blocks fit per CU (16 waves/CU) instead of 2 (8 waves).
// Read-phase work is split by WAVE (waves 0,1 take rows 0..31; waves 2,3
// take rows 32..63) so there is no intra-wave divergence.

__global__ void setup_uf(const float* __restrict__ phi_x,
                         const float* __restrict__ phi_y,
                         float* __restrict__ ws) {
    const int t = threadIdx.x;
    if (t < 2) {
        const float* phi = (t == 0) ? phi_x : phi_y;
        float U[8][8];
#pragma unroll
        for (int i = 0; i < 8; ++i)
#pragma unroll
            for (int j = 0; j < 8; ++j) U[i][j] = (i == j) ? 1.0f : 0.0f;
        int idx = 0;
#pragma unroll
        for (int i = 1; i < 8; ++i) {
#pragma unroll
            for (int j = i; j >= 1; --j) {
                const float c = cosf(phi[idx]);
                const float s = sinf(phi[idx]);
#pragma unroll
                for (int m = 0; m < 8; ++m) {
                    const float a = U[j - 1][m], b = U[j][m];
                    U[j - 1][m] = c * a + s * b;
                    U[j][m]     = -s * a + c * b;
                }
                ++idx;
            }
        }
        float* o = ws + t * 64;
#pragma unroll
        for (int i = 0; i < 8; ++i)
#pragma unroll
            for (int j = 0; j < 8; ++j) o[i * 8 + j] = U[i][j];
    }
}

// contract the INNER index (stride 1 within groups of 8) of a[64] with M[8][8]
#define CONTRACT_INNER(M, a)                                                   \
    _Pragma("unroll")                                                          \
    for (int _g = 0; _g < 8; ++_g) {                                           \
        float _tmp[8];                                                         \
        _Pragma("unroll")                                                      \
        for (int _i = 0; _i < 8; ++_i) {                                       \
            float _acc = 0.0f;                                                 \
            _Pragma("unroll")                                                  \
            for (int _k = 0; _k < 8; ++_k)                                     \
                _acc = fmaf((M)[_i * 8 + _k], (a)[_g * 8 + _k], _acc);         \
            _tmp[_i] = _acc;                                                   \
        }                                                                      \
        _Pragma("unroll")                                                      \
        for (int _i = 0; _i < 8; ++_i) (a)[_g * 8 + _i] = _tmp[_i];            \
    }

// contract the OUTER index (stride 8) of a[64] with M[8][8]
#define CONTRACT_OUTER(M, a)                                                   \
    _Pragma("unroll")                                                          \
    for (int _g = 0; _g < 8; ++_g) {                                           \
        float _tmp[8];                                                         \
        _Pragma("unroll")                                                      \
        for (int _i = 0; _i < 8; ++_i) {                                       \
            float _acc = 0.0f;                                                 \
            _Pragma("unroll")                                                  \
            for (int _k = 0; _k < 8; ++_k)                                     \
                _acc = fmaf((M)[_i * 8 + _k], (a)[_k * 8 + _g], _acc);         \
            _tmp[_i] = _acc;                                                   \
        }                                                                      \
        _Pragma("unroll")                                                      \
        for (int _i = 0; _i < 8; ++_i) (a)[_i * 8 + _g] = _tmp[_i];            \
    }

// Column (y2,x2) transform + direct store for one (rr, by2) unit.
// S holds 32 swizzled rows with base row (rr & ~31).
__device__ __forceinline__ void col_phase(const float* __restrict__ S,
                                          const float* __restrict__ UX,
                                          const float* __restrict__ UY,
                                          float* __restrict__ out,
                                          size_t B0, int rowbase, int bx2,
                                          int rr, int by2) {
    const int r2 = rr & 31;
    const int r7 = r2 & 7;
    float p[64];
#pragma unroll
    for (int x = 0; x < 8; ++x) {
        const int cc0 = (((x * 8 + by2 * 2 + 0) ^ r7) << 2);
        const int cc1 = (((x * 8 + by2 * 2 + 1) ^ r7) << 2);
        const float4 q0 = *reinterpret_cast<const float4*>(&S[r2 * 256 + cc0]);
        const float4 q1 = *reinterpret_cast<const float4*>(&S[r2 * 256 + cc1]);
        p[x * 8 + 0] = q0.x; p[x * 8 + 1] = q0.y;
        p[x * 8 + 2] = q0.z; p[x * 8 + 3] = q0.w;
        p[x * 8 + 4] = q1.x; p[x * 8 + 5] = q1.y;
        p[x * 8 + 6] = q1.z; p[x * 8 + 7] = q1.w;
    }

    CONTRACT_INNER(UY, p)
    CONTRACT_OUTER(UX, p)

    const int gr = rowbase + ((rr >> 3) * 32) + (rr & 7);
    float* __restrict__ dst = out + B0 + (size_t)gr * 1024 + bx2 * 256 + by2 * 8;
#pragma unroll
    for (int x = 0; x < 8; ++x) {
        *reinterpret_cast<float4*>(dst + x * 32) =
            make_float4(p[x * 8 + 0], p[x * 8 + 1], p[x * 8 + 2], p[x * 8 + 3]);
        *reinterpret_cast<float4*>(dst + x * 32 + 4) =
            make_float4(p[x * 8 + 4], p[x * 8 + 5], p[x * 8 + 6], p[x * 8 + 7]);
    }
}

__global__ __launch_bounds__(256, 4) void qconv_fused(const float* __restrict__ rho,
                                                      const float* __restrict__ ws,
                                                      float* __restrict__ out) {
    __shared__ float S[8192];  // [32 rows][256 cols] swizzled = 32 KB
    const int t   = threadIdx.x;
    const int bid = blockIdx.x;
    const int bx2 = bid & 3;
    const int by1 = (bid >> 2) & 3;
    const int bx1 = (bid >> 4) & 3;
    const int b   = bid >> 6;

    const float* __restrict__ UX = ws;       // Ufx[8][8] (wave-uniform -> s_load)
    const float* __restrict__ UY = ws + 64;  // Ufy[8][8]

    const size_t B0      = (size_t)b << 20;
    const int    rowbase = bx1 * 256 + by1 * 8;
    const int    cg      = bx2 * 256 + t;

    // ---- load 64 rows at column cg (coalesced dwords) ----
    const float* __restrict__ src = rho + B0 + (size_t)rowbase * 1024 + cg;
    float v[64];
#pragma unroll
    for (int i = 0; i < 8; ++i)
#pragma unroll
        for (int j = 0; j < 8; ++j)
            v[i * 8 + j] = src[(i * 32 + j) * 1024];

    // ---- row transform in registers: y1 (inner), x1 (outer) ----
    CONTRACT_INNER(UY, v)
    CONTRACT_OUTER(UX, v)

    // swizzled column slot per row-parity: chunk (t>>2) XOR'd by (r&7)
    int cswz[8];
#pragma unroll
    for (int r7 = 0; r7 < 8; ++r7)
        cswz[r7] = ((((t >> 2) ^ r7) << 2) | (t & 3));

    // ---- half-pass 1: rows 0..31 ----
#pragma unroll
    for (int r = 0; r < 32; ++r) S[r * 256 + cswz[r & 7]] = v[r];
    __syncthreads();

    const int wid = t >> 6;
    if (wid < 2) {
        // waves 0,1: rr in [0,32), by2 = t>>5 in [0,4)
        col_phase(S, UX, UY, out, B0, rowbase, bx2, t & 31, t >> 5);
    }
    __syncthreads();

    // ---- half-pass 2: rows 32..63 ----
#pragma unroll
    for (int r = 32; r < 64; ++r) S[(r - 32) * 256 + cswz[r & 7]] = v[r];
    __syncthreads();

    if (wid >= 2) {
        const int u = t - 128;
        col_phase(S, UX, UY, out, B0, rowbase, bx2, 32 + (u & 31), u >> 5);
    }
}

extern "C" void kernel_launch(void* const* d_in, const int* in_sizes, int n_in,
                              void* d_out, int out_size, void* d_ws, size_t ws_size,
                              hipStream_t stream) {
    const float* rho   = (const float*)d_in[0];
    const float* phi_x = (const float*)d_in[1];
    const float* phi_y = (const float*)d_in[2];
    float* out = (float*)d_out;
    float* ws  = (float*)d_ws;

    setup_uf<<<1, 64, 0, stream>>>(phi_x, phi_y, ws);
    qconv_fused<<<1024, 256, 0, stream>>>(rho, ws, out);
}